// Round 7
// baseline (156.788 us; speedup 1.0000x reference)
//
#include <hip/hip_runtime.h>
#include <cstdint>

// ---------------- problem constants ----------------
#define D_MODEL 1024
#define NHEADS  16
#define DKH     64
#define SEQ     2048
#define NBATCH  2
#define MROWS   (NBATCH*SEQ)   // 4096
#define RTYPES  8
#define LOG2E   1.44269504f

typedef __bf16 bf16;
typedef __bf16 bf16x4v __attribute__((ext_vector_type(4)));
typedef __bf16 bf16x8v __attribute__((ext_vector_type(8)));
typedef float  f32x4v  __attribute__((ext_vector_type(4)));
typedef float  f32x16v __attribute__((ext_vector_type(16)));

typedef unsigned int __attribute__((address_space(1))) as1_u32;
typedef unsigned int __attribute__((address_space(3))) as3_u32;

static __device__ __forceinline__ void gload_lds16(const void* g, void* l) {
  __builtin_amdgcn_global_load_lds((const as1_u32*)(uintptr_t)g,
                                   (as3_u32*)(uintptr_t)l, 16, 0, 0);
}

static __device__ __forceinline__ f32x4v mfma16(bf16x8v a, bf16x8v b, f32x4v c) {
  return __builtin_amdgcn_mfma_f32_16x16x32_bf16(a, b, c, 0, 0, 0);
}
static __device__ __forceinline__ f32x16v mfma32(bf16x8v a, bf16x8v b, f32x16v c) {
  return __builtin_amdgcn_mfma_f32_32x32x16_bf16(a, b, c, 0, 0, 0);
}

// ---------------- fp32->bf16 conversion + bias precompute (flat 1D grid) --------
__global__ void convert_kernel(const float* __restrict__ x,  const float* __restrict__ wq,
                               const float* __restrict__ wk, const float* __restrict__ wv,
                               const float* __restrict__ wo,
                               bf16* __restrict__ xb,  bf16* __restrict__ wqb,
                               bf16* __restrict__ wkb, bf16* __restrict__ wvb,
                               bf16* __restrict__ wob,
                               const float* __restrict__ rbias,
                               const int* __restrict__ rmask,
                               const int* __restrict__ amask,
                               float* __restrict__ biasg)
{
  int idx = blockIdx.x*256 + threadIdx.x;
  if (idx < 1048576){
    float4 v = ((const float4*)x)[idx];
    bf16x4v o = { (bf16)v.x, (bf16)v.y, (bf16)v.z, (bf16)v.w };
    ((bf16x4v*)xb)[idx] = o;
  } else if (idx < 2097152){
    int r = (idx - 1048576) >> 18;
    int i = (idx - 1048576) & 262143;
    const float* src; bf16* dst;
    if (r == 0)      { src = wq; dst = wqb; }
    else if (r == 1) { src = wk; dst = wkb; }
    else if (r == 2) { src = wv; dst = wvb; }
    else             { src = wo; dst = wob; }
    float4 v = ((const float4*)src)[i];
    bf16x4v o = { (bf16)v.x, (bf16)v.y, (bf16)v.z, (bf16)v.w };
    ((bf16x4v*)dst)[i] = o;
  } else {
    int i = idx - 2097152;
    #pragma unroll
    for (int bb=0; bb<NBATCH; bb++){
      int id2 = bb*(NHEADS*RTYPES*SEQ) + i;
      int j  = id2 & (SEQ-1);
      int t  = (id2 >> 11) & 7;
      int hh = (id2 >> 14) & 15;
      int rj = rmask[bb*SEQ + j];
      float am = amask[bb*SEQ + j] ? 0.f : -1e9f;
      biasg[id2] = (rbias[(hh*RTYPES + t)*RTYPES + rj] + am) * LOG2E;
    }
  }
}

// ---------------- NT GEMM, 2-phase double-buffered (unchanged) ----------------
struct GemmOuts { const bf16* W[3]; const float* bia[3]; void* out[3]; };

template<int FUSED>
__global__ __launch_bounds__(256, 3) void gemm_bt_kernel(
    const bf16* __restrict__ A, GemmOuts args, float qscale)
{
  const int K  = D_MODEL;
  const int z  = FUSED ? blockIdx.z : 0;
  const bf16*  Bw   = args.W[z];
  const float* bias = args.bia[z];
  void* outp        = args.out[z];
  const float scale = (FUSED && z==0) ? qscale : 1.0f;

  const int n0 = blockIdx.x*128, m0 = blockIdx.y*128;
  const int tid = threadIdx.x;
  const int w = tid>>6, lane = tid&63, g = lane>>4, c = lane&15;
  const int wm = w>>1, wn = w&1;

  __shared__ __align__(16) bf16 a_lds[2][128*32];
  __shared__ __align__(16) bf16 b_lds[2][128*32];

  const f32x4v fzero = {0.f,0.f,0.f,0.f};
  f32x4v acc[4][4];
  for (int i=0;i<4;i++) for (int j=0;j<4;j++) acc[i][j] = fzero;

  const int srow = tid>>2, sc8 = tid&3;

  auto STAGE = [&](int k0, int nb){
    gload_lds16(A  + (size_t)(m0+srow)*K     + k0 + sc8*8, &a_lds[nb][(w*64)*8]);
    gload_lds16(Bw + (size_t)(n0+srow)*K     + k0 + sc8*8, &b_lds[nb][(w*64)*8]);
    gload_lds16(A  + (size_t)(m0+64+srow)*K  + k0 + sc8*8, &a_lds[nb][(256 + w*64)*8]);
    gload_lds16(Bw + (size_t)(n0+64+srow)*K  + k0 + sc8*8, &b_lds[nb][(256 + w*64)*8]);
  };

  auto COMPUTE = [&](int nb){
    bf16x8v af[4], bfv[4];
    #pragma unroll
    for (int mt=0;mt<4;mt++)
      af[mt] = *(const bf16x8v*)&a_lds[nb][(wm*64 + mt*16 + c)*32 + g*8];
    #pragma unroll
    for (int nt=0;nt<4;nt++)
      bfv[nt] = *(const bf16x8v*)&b_lds[nb][(wn*64 + nt*16 + c)*32 + g*8];
    #pragma unroll
    for (int mt=0;mt<4;mt++)
      #pragma unroll
      for (int nt=0;nt<4;nt++)
        acc[mt][nt] = mfma16(af[mt], bfv[nt], acc[mt][nt]);
  };

  STAGE(0, 0);
  __syncthreads();
  int cur = 0;
  for (int k0=32; k0<K; k0+=32){
    STAGE(k0, cur^1);
    COMPUTE(cur);
    __syncthreads();
    cur ^= 1;
  }
  COMPUTE(cur);

  #pragma unroll
  for (int mt=0;mt<4;mt++){
    #pragma unroll
    for (int nt=0;nt<4;nt++){
      if (FUSED && z == 2){
        int m = m0 + wm*64 + mt*16 + g*4;
        int n = n0 + wn*64 + nt*16 + c;
        int bb=m>>11, s=m&2047, hh=n>>6, dk=n&63;
        float bn = bias[n];
        bf16x4v ov;
        #pragma unroll
        for (int r=0;r<4;r++) ov[r] = (bf16)(acc[mt][nt][r] + bn);
        *(bf16x4v*)&((bf16*)outp)[(((size_t)bb*NHEADS+hh)*DKH + dk)*SEQ + s] = ov;
      } else {
        #pragma unroll
        for (int r=0;r<4;r++){
          int m = m0 + wm*64 + mt*16 + g*4 + r;
          int n = n0 + wn*64 + nt*16 + c;
          float v = acc[mt][nt][r] + bias[n];
          if (FUSED){
            v *= scale;
            int bb=m>>11, s=m&2047, hh=n>>6, dk=n&63;
            ((bf16*)outp)[(((size_t)bb*NHEADS+hh)*SEQ + s)*DKH + dk] = (bf16)v;
          } else {
            ((float*)outp)[(size_t)m*D_MODEL + n] = v;
          }
        }
      }
    }
  }
}

// ---------------- flash attention v6: d-major conflict-free LDS, reg-bias ------
// grid (SEQ/128, NHEADS, NBATCH) x 256 (4 waves x 32 q-rows).
// LDS layout (K and V^T, per 64x64 tile): phys byte = dblk*1024 + row*16
//   (dblk = 8-bf16 column block). QK/PV reads are 32 contiguous 16B chunks per
//   hi-half -> bank-conflict-free. K rows sigma-permuted (bit2<->bit3) at the
//   staging SOURCE so PV B-fragments are register renames of S (as v5).
// Bias: per-lane global gathers (L2), software-prefetched 1 tile ahead into
//   regs, used as MFMA C-init. No bias LDS, no bias staging.
// Pipeline: 3-buf, 2-ahead staging; compiler-inserted vmcnt for the bias regs
//   provably drains staging(t+1) before each barrier (bias(t) issued after
//   STAGE(t+1) in program order); manual vmcnt only in prologue.
__global__ __launch_bounds__(256, 2) void attn6_kernel(
    const bf16* __restrict__ Qg, const bf16* __restrict__ Kg,
    const bf16* __restrict__ Vtg, const float* __restrict__ biasg,
    const int* __restrict__ rmask, bf16* __restrict__ Og)
{
  const int b = blockIdx.z, h = blockIdx.y, q0 = blockIdx.x*128;
  const int tid = threadIdx.x;
  const int w = tid>>6, lane = tid&63;
  const int q5 = lane&31, hi = lane>>5;
  const int bh = b*NHEADS + h;
  const int NT = SEQ/64;

  __shared__ __align__(16) bf16 k_lds[3][64*64];    // 8KB/buf, d-major slabs
  __shared__ __align__(16) bf16 vt_lds[3][64*64];

  // Q fragments (B-operand): col=q5, k = hi*8+e; frag kc covers d = kc*16+hi*8+0..7
  const int qrow = q0 + w*32 + q5;
  const bf16* qptr = Qg + ((size_t)bh*SEQ + qrow)*DKH;
  bf16x8v qf[4];
  #pragma unroll
  for (int kc=0;kc<4;kc++)
    qf[kc] = *(const bf16x8v*)(qptr + kc*16 + hi*8);

  const int tq = rmask[b*SEQ + qrow];
  const float* bptrL = biasg + (size_t)(bh*RTYPES + tq)*SEQ;   // lane-dep bias row

  // staging source pointers (lane-dep, tile-invariant)
  const int sig = (lane & 0x33) | ((lane & 8) >> 1) | ((lane & 4) << 1); // swap b2<->b3
  const bf16* ksrcL = Kg  + ((size_t)bh*SEQ + sig)*DKH;
  const bf16* vsrcL = Vtg + ((size_t)bh*DKH + lane)*SEQ;

  const int lbase = hi*512 + q5*8;    // LDS element base for reads

  bf16x8v ones;
  #pragma unroll
  for (int i=0;i<8;i++) ones[i] = (bf16)1.0f;

  f32x16v oacc0, oacc1, lacc;
  #pragma unroll
  for (int r=0;r<16;r++){ oacc0[r]=0.f; oacc1[r]=0.f; lacc[r]=0.f; }
  float mrow = -1e30f;

  auto STAGE = [&](int j0, int nb){
    #pragma unroll
    for (int i=0;i<2;i++){
      const int dblk = i*4 + w;
      gload_lds16(ksrcL + (size_t)j0*DKH + dblk*8, &k_lds[nb][(i*256 + w*64)*8]);
      gload_lds16(vsrcL + j0 + dblk*8,             &vt_lds[nb][(i*256 + w*64)*8]);
    }
  };

  f32x4v bv[2][4];    // prefetched bias (static indexing only)
  auto BIAS_LOAD = [&](int j0){
    #pragma unroll
    for (int nt=0;nt<2;nt++){
      const float* bpn = bptrL + j0 + nt*32 + hi*8;
      bv[nt][0] = *(const f32x4v*)(bpn + 0);
      bv[nt][1] = *(const f32x4v*)(bpn + 4);
      bv[nt][2] = *(const f32x4v*)(bpn + 16);
      bv[nt][3] = *(const f32x4v*)(bpn + 20);
    }
  };

  // ---- prologue: STAGE(0); bias(0); STAGE(1); wait stage0; barrier ----
  STAGE(0, 0);
  BIAS_LOAD(0);
  STAGE(64, 1);
  asm volatile("s_waitcnt vmcnt(4)" ::: "memory");  // stage0+bias done, stage1 may fly
  __builtin_amdgcn_s_barrier();

  int cur = 0;
  #pragma unroll 1
  for (int t=0; t<NT; ++t){
    if (t+2 < NT){
      int nb2 = cur+2; if (nb2 >= 3) nb2 -= 3;
      STAGE((t+2)*64, nb2);
    }
    {
      const bf16* kb_ = &k_lds[cur][0];
      const bf16* vb_ = &vt_lds[cur][0];

      // C-init from prefetched bias (reg->reg), then prefetch next tile's bias
      f32x16v s0, s1;
      #pragma unroll
      for (int g4=0; g4<4; g4++)
        #pragma unroll
        for (int rr=0; rr<4; rr++){
          s0[g4*4+rr] = bv[0][g4][rr];
          s1[g4*4+rr] = bv[1][g4][rr];
        }
      BIAS_LOAD((t+1 < NT) ? (t+1)*64 : t*64);

      // S^T = K Q^T (+bias); s[nt] reg r: j = nt*32+(r&3)+4*((r>>2)&1)+8*hi+16*(r>>3)
      #pragma unroll
      for (int kc=0;kc<4;kc++){
        bf16x8v kf0 = *(const bf16x8v*)(kb_ + lbase + kc*1024);
        bf16x8v kf1 = *(const bf16x8v*)(kb_ + lbase + kc*1024 + 256);
        s0 = mfma32(kf0, qf[kc], s0);
        s1 = mfma32(kf1, qf[kc], s1);
      }

      // row max: max3 tree + 1 cross-half shuffle
      float a0 = fmaxf(fmaxf(s0[0],s0[1]),s0[2]);
      float a1 = fmaxf(fmaxf(s0[3],s0[4]),s0[5]);
      float a2 = fmaxf(fmaxf(s0[6],s0[7]),s0[8]);
      float a3 = fmaxf(fmaxf(s0[9],s0[10]),s0[11]);
      float a4 = fmaxf(fmaxf(s0[12],s0[13]),s0[14]);
      float a5 = fmaxf(fmaxf(s0[15],s1[0]),s1[1]);
      float a6 = fmaxf(fmaxf(s1[2],s1[3]),s1[4]);
      float a7 = fmaxf(fmaxf(s1[5],s1[6]),s1[7]);
      float a8 = fmaxf(fmaxf(s1[8],s1[9]),s1[10]);
      float a9 = fmaxf(fmaxf(s1[11],s1[12]),s1[13]);
      float aA = fmaxf(s1[14],s1[15]);
      float b0 = fmaxf(fmaxf(a0,a1),a2);
      float b1 = fmaxf(fmaxf(a3,a4),a5);
      float b2 = fmaxf(fmaxf(a6,a7),a8);
      float b3 = fmaxf(a9,aA);
      float mx = fmaxf(fmaxf(b0,b1), fmaxf(b2,b3));
      mx = fmaxf(mx, __shfl_xor(mx, 32));

      // defer-max (THR=8, exp2 units)
      if (!__all(mx - mrow <= 8.0f)){
        float mnew = fmaxf(mrow, mx);
        float scl = exp2f(mrow - mnew);
        #pragma unroll
        for (int r=0;r<16;r++){ oacc0[r] *= scl; oacc1[r] *= scl; lacc[r] *= scl; }
        mrow = mnew;
      }

      #pragma unroll
      for (int r=0;r<16;r++){ s0[r] = exp2f(s0[r] - mrow); s1[r] = exp2f(s1[r] - mrow); }

      // P fragments: contiguous register renames
      bf16x8v pa0, pa1, pa2, pa3;
      #pragma unroll
      for (int e=0;e<8;e++){
        pa0[e] = (bf16)s0[e];   pa1[e] = (bf16)s0[e+8];
        pa2[e] = (bf16)s1[e];   pa3[e] = (bf16)s1[e+8];
      }

      // row-sum on MFMA pipe
      lacc = mfma32(ones, pa0, lacc);
      lacc = mfma32(ones, pa1, lacc);
      lacc = mfma32(ones, pa2, lacc);
      lacc = mfma32(ones, pa3, lacc);

      // O^T += V^T P  (A-frag row=d=dt*32+q5, j-block m*2+hi)
      #pragma unroll
      for (int m=0;m<4;m++){
        bf16x8v vf0 = *(const bf16x8v*)(vb_ + lbase + m*1024);
        bf16x8v vf1 = *(const bf16x8v*)(vb_ + lbase + m*1024 + 256);
        bf16x8v pm = (m==0)?pa0:(m==1)?pa1:(m==2)?pa2:pa3;
        oacc0 = mfma32(vf0, pm, oacc0);
        oacc1 = mfma32(vf1, pm, oacc1);
      }
    }
    __builtin_amdgcn_s_barrier();
    cur = (cur+1 == 3) ? 0 : cur+1;
  }

  // normalize + store: lane holds O^T[d = dt*32+(r&3)+8*(r>>2)+4*hi][q=q5]
  const float inv = 1.0f / lacc[0];
  #pragma unroll
  for (int rq=0;rq<4;rq++){
    bf16x4v ov0, ov1;
    #pragma unroll
    for (int k=0;k<4;k++){ ov0[k] = (bf16)(oacc0[rq*4+k] * inv);
                           ov1[k] = (bf16)(oacc1[rq*4+k] * inv); }
    const int d = 8*rq + 4*hi;
    bf16* orow = &Og[(size_t)(b*SEQ + qrow)*D_MODEL + h*DKH];
    *(bf16x4v*)(orow + d)      = ov0;
    *(bf16x4v*)(orow + 32 + d) = ov1;
  }
}

// ---------------- launch ----------------
extern "C" void kernel_launch(void* const* d_in, const int* in_sizes, int n_in,
                              void* d_out, int out_size, void* d_ws, size_t ws_size,
                              hipStream_t stream)
{
  (void)in_sizes; (void)n_in; (void)out_size; (void)ws_size;
  const float* x     = (const float*)d_in[0];
  const float* Wq    = (const float*)d_in[1];
  const float* bq    = (const float*)d_in[2];
  const float* Wk    = (const float*)d_in[3];
  const float* bk    = (const float*)d_in[4];
  const float* Wv    = (const float*)d_in[5];
  const float* bv    = (const float*)d_in[6];
  const float* Wo    = (const float*)d_in[7];
  const float* bo    = (const float*)d_in[8];
  const float* rbias = (const float*)d_in[9];
  const int*   rmask = (const int*)d_in[10];
  const int*   amask = (const int*)d_in[11];
  float* out = (float*)d_out;

  char* ws = (char*)d_ws;
  bf16*  xb    = (bf16*)(ws);                 //  8 MB
  bf16*  wqb   = (bf16*)(ws + (8u<<20));      //  2 MB each
  bf16*  wkb   = (bf16*)(ws + (10u<<20));
  bf16*  wvb   = (bf16*)(ws + (12u<<20));
  bf16*  wob   = (bf16*)(ws + (14u<<20));
  bf16*  qb    = (bf16*)(ws + (16u<<20));     //  8 MB Q (pre-scaled, exp2 domain)
  bf16*  kb    = (bf16*)(ws + (24u<<20));     //  8 MB K
  bf16*  vtb   = (bf16*)(ws + (32u<<20));     //  8 MB V^T
  bf16*  aob   = (bf16*)(ws + (40u<<20));     //  8 MB attn out [s][e]
  float* biasg = (float*)(ws + (48u<<20));    //  2 MB bias [b][h][8][S]

  convert_kernel<<<9216, 256, 0, stream>>>(x,Wq,Wk,Wv,Wo, xb,wqb,wkb,wvb,wob,
                                           rbias, rmask, amask, biasg);

  GemmOuts qkv;
  qkv.W[0]=wqb; qkv.W[1]=wkb; qkv.W[2]=wvb;
  qkv.bia[0]=bq; qkv.bia[1]=bk; qkv.bia[2]=bv;
  qkv.out[0]=qb; qkv.out[1]=kb; qkv.out[2]=vtb;
  gemm_bt_kernel<1><<<dim3(D_MODEL/128, MROWS/128, 3), 256, 0, stream>>>(xb, qkv, 0.125f*LOG2E);

  attn6_kernel<<<dim3(SEQ/128, NHEADS, NBATCH), 256, 0, stream>>>(qb, kb, vtb, biasg, rmask, aob);

  GemmOuts og;
  og.W[0]=wob; og.W[1]=wob; og.W[2]=wob;
  og.bia[0]=bo; og.bia[1]=bo; og.bia[2]=bo;
  og.out[0]=out; og.out[1]=out; og.out[2]=out;
  gemm_bt_kernel<0><<<dim3(D_MODEL/128, MROWS/128), 256, 0, stream>>>(aob, og, 1.0f);
}

// Round 9
// 134.476 us; speedup vs baseline: 1.1659x; 1.1659x over previous
//
#include <hip/hip_runtime.h>
#include <cstdint>

// ---------------- problem constants ----------------
#define D_MODEL 1024
#define NHEADS  16
#define DKH     64
#define SEQ     2048
#define NBATCH  2
#define MROWS   (NBATCH*SEQ)   // 4096
#define RTYPES  8
#define LOG2E   1.44269504f

typedef __bf16 bf16;
typedef __bf16 bf16x4v __attribute__((ext_vector_type(4)));
typedef __bf16 bf16x8v __attribute__((ext_vector_type(8)));
typedef float  f32x4v  __attribute__((ext_vector_type(4)));
typedef float  f32x16v __attribute__((ext_vector_type(16)));

typedef unsigned int __attribute__((address_space(1))) as1_u32;
typedef unsigned int __attribute__((address_space(3))) as3_u32;

static __device__ __forceinline__ void gload_lds16(const void* g, void* l) {
  __builtin_amdgcn_global_load_lds((const as1_u32*)(uintptr_t)g,
                                   (as3_u32*)(uintptr_t)l, 16, 0, 0);
}

static __device__ __forceinline__ f32x4v mfma16(bf16x8v a, bf16x8v b, f32x4v c) {
  return __builtin_amdgcn_mfma_f32_16x16x32_bf16(a, b, c, 0, 0, 0);
}
static __device__ __forceinline__ f32x16v mfma32(bf16x8v a, bf16x8v b, f32x16v c) {
  return __builtin_amdgcn_mfma_f32_32x32x16_bf16(a, b, c, 0, 0, 0);
}

// ---------------- fp32->bf16 conversion + bias precompute (flat 1D grid) --------
__global__ void convert_kernel(const float* __restrict__ x,  const float* __restrict__ wq,
                               const float* __restrict__ wk, const float* __restrict__ wv,
                               const float* __restrict__ wo,
                               bf16* __restrict__ xb,  bf16* __restrict__ wqb,
                               bf16* __restrict__ wkb, bf16* __restrict__ wvb,
                               bf16* __restrict__ wob,
                               const float* __restrict__ rbias,
                               const int* __restrict__ rmask,
                               const int* __restrict__ amask,
                               float* __restrict__ biasg)
{
  int idx = blockIdx.x*256 + threadIdx.x;
  if (idx < 1048576){
    float4 v = ((const float4*)x)[idx];
    bf16x4v o = { (bf16)v.x, (bf16)v.y, (bf16)v.z, (bf16)v.w };
    ((bf16x4v*)xb)[idx] = o;
  } else if (idx < 2097152){
    int r = (idx - 1048576) >> 18;
    int i = (idx - 1048576) & 262143;
    const float* src; bf16* dst;
    if (r == 0)      { src = wq; dst = wqb; }
    else if (r == 1) { src = wk; dst = wkb; }
    else if (r == 2) { src = wv; dst = wvb; }
    else             { src = wo; dst = wob; }
    float4 v = ((const float4*)src)[i];
    bf16x4v o = { (bf16)v.x, (bf16)v.y, (bf16)v.z, (bf16)v.w };
    ((bf16x4v*)dst)[i] = o;
  } else {
    int i = idx - 2097152;
    #pragma unroll
    for (int bb=0; bb<NBATCH; bb++){
      int id2 = bb*(NHEADS*RTYPES*SEQ) + i;
      int j  = id2 & (SEQ-1);
      int t  = (id2 >> 11) & 7;
      int hh = (id2 >> 14) & 15;
      int rj = rmask[bb*SEQ + j];
      float am = amask[bb*SEQ + j] ? 0.f : -1e9f;
      biasg[id2] = (rbias[(hh*RTYPES + t)*RTYPES + rj] + am) * LOG2E;
    }
  }
}

// ---------------- NT GEMM, 2-phase double-buffered (unchanged) ----------------
struct GemmOuts { const bf16* W[3]; const float* bia[3]; void* out[3]; };

template<int FUSED>
__global__ __launch_bounds__(256, 3) void gemm_bt_kernel(
    const bf16* __restrict__ A, GemmOuts args, float qscale)
{
  const int K  = D_MODEL;
  const int z  = FUSED ? blockIdx.z : 0;
  const bf16*  Bw   = args.W[z];
  const float* bias = args.bia[z];
  void* outp        = args.out[z];
  const float scale = (FUSED && z==0) ? qscale : 1.0f;

  const int n0 = blockIdx.x*128, m0 = blockIdx.y*128;
  const int tid = threadIdx.x;
  const int w = tid>>6, lane = tid&63, g = lane>>4, c = lane&15;
  const int wm = w>>1, wn = w&1;

  __shared__ __align__(16) bf16 a_lds[2][128*32];
  __shared__ __align__(16) bf16 b_lds[2][128*32];

  const f32x4v fzero = {0.f,0.f,0.f,0.f};
  f32x4v acc[4][4];
  for (int i=0;i<4;i++) for (int j=0;j<4;j++) acc[i][j] = fzero;

  const int srow = tid>>2, sc8 = tid&3;

  auto STAGE = [&](int k0, int nb){
    gload_lds16(A  + (size_t)(m0+srow)*K     + k0 + sc8*8, &a_lds[nb][(w*64)*8]);
    gload_lds16(Bw + (size_t)(n0+srow)*K     + k0 + sc8*8, &b_lds[nb][(w*64)*8]);
    gload_lds16(A  + (size_t)(m0+64+srow)*K  + k0 + sc8*8, &a_lds[nb][(256 + w*64)*8]);
    gload_lds16(Bw + (size_t)(n0+64+srow)*K  + k0 + sc8*8, &b_lds[nb][(256 + w*64)*8]);
  };

  auto COMPUTE = [&](int nb){
    bf16x8v af[4], bfv[4];
    #pragma unroll
    for (int mt=0;mt<4;mt++)
      af[mt] = *(const bf16x8v*)&a_lds[nb][(wm*64 + mt*16 + c)*32 + g*8];
    #pragma unroll
    for (int nt=0;nt<4;nt++)
      bfv[nt] = *(const bf16x8v*)&b_lds[nb][(wn*64 + nt*16 + c)*32 + g*8];
    #pragma unroll
    for (int mt=0;mt<4;mt++)
      #pragma unroll
      for (int nt=0;nt<4;nt++)
        acc[mt][nt] = mfma16(af[mt], bfv[nt], acc[mt][nt]);
  };

  STAGE(0, 0);
  __syncthreads();
  int cur = 0;
  for (int k0=32; k0<K; k0+=32){
    STAGE(k0, cur^1);
    COMPUTE(cur);
    __syncthreads();
    cur ^= 1;
  }
  COMPUTE(cur);

  #pragma unroll
  for (int mt=0;mt<4;mt++){
    #pragma unroll
    for (int nt=0;nt<4;nt++){
      if (FUSED && z == 2){
        int m = m0 + wm*64 + mt*16 + g*4;
        int n = n0 + wn*64 + nt*16 + c;
        int bb=m>>11, s=m&2047, hh=n>>6, dk=n&63;
        float bn = bias[n];
        bf16x4v ov;
        #pragma unroll
        for (int r=0;r<4;r++) ov[r] = (bf16)(acc[mt][nt][r] + bn);
        *(bf16x4v*)&((bf16*)outp)[(((size_t)bb*NHEADS+hh)*DKH + dk)*SEQ + s] = ov;
      } else {
        #pragma unroll
        for (int r=0;r<4;r++){
          int m = m0 + wm*64 + mt*16 + g*4 + r;
          int n = n0 + wn*64 + nt*16 + c;
          float v = acc[mt][nt][r] + bias[n];
          if (FUSED){
            v *= scale;
            int bb=m>>11, s=m&2047, hh=n>>6, dk=n&63;
            ((bf16*)outp)[(((size_t)bb*NHEADS+hh)*SEQ + s)*DKH + dk] = (bf16)v;
          } else {
            ((float*)outp)[(size_t)m*D_MODEL + n] = v;
          }
        }
      }
    }
  }
}

// ---------------- flash attention v7: in-block j-split (8 waves), LSE merge ----
// grid (SEQ/128, NHEADS, NBATCH) x 512. Waves 0-3: j in [0,1024); waves 4-7:
// j in [1024,2048); same 128 q-rows. 16 waves/CU (4/SIMD) for latency hiding.
// Per half: d-major conflict-free K/V LDS (v6 layout, sigma-permuted K rows at
// staging source), v5's LDS-staged bias (tq-XOR swizzle, bias = MFMA C-init).
// m97-style 2-buffer: STAGE(t+1) -> COMPUTE(t) -> __syncthreads per tile.
// Block-end: halves merge via LDS (log-sum-exp combine), waves 0-3 store.
__global__ __launch_bounds__(512, 4) void attn7_kernel(
    const bf16* __restrict__ Qg, const bf16* __restrict__ Kg,
    const bf16* __restrict__ Vtg, const float* __restrict__ biasg,
    const int* __restrict__ rmask, bf16* __restrict__ Og)
{
  const int b = blockIdx.z, h = blockIdx.y, q0 = blockIdx.x*128;
  const int tid = threadIdx.x;
  const int w = tid>>6, lane = tid&63;
  const int half = w>>2, wl = w&3;
  const int q5 = lane&31, hi = lane>>5;
  const int bh = b*NHEADS + h;
  const int NTl = 16;                          // tiles per half

  __shared__ __align__(16) bf16  kv_lds[2][2][2][4096];  // [half][buf][K/V] 64KB
  __shared__ __align__(16) float bias_lds[2][2][512];    //  8KB

  // Q fragments (B-operand): col=q5, frag kc covers d = kc*16+hi*8+0..7
  const int qrow = q0 + wl*32 + q5;
  const bf16* qptr = Qg + ((size_t)bh*SEQ + qrow)*DKH;
  bf16x8v qf[4];
  #pragma unroll
  for (int kc=0;kc<4;kc++)
    qf[kc] = *(const bf16x8v*)(qptr + kc*16 + hi*8);

  const int tq = rmask[b*SEQ + qrow];

  // bias C-init word offsets into the half's 512-float buffer
  int boff[2][4];
  #pragma unroll
  for (int nt=0;nt<2;nt++){
    const int j00 = nt*32 + hi*8;
    boff[nt][0] = tq*64 + ((j00 +  0) ^ (tq*8));
    boff[nt][1] = tq*64 + ((j00 +  4) ^ (tq*8));
    boff[nt][2] = tq*64 + ((j00 + 16) ^ (tq*8));
    boff[nt][3] = tq*64 + ((j00 + 20) ^ (tq*8));
  }

  f32x16v oacc0, oacc1;
  #pragma unroll
  for (int r=0;r<16;r++){ oacc0[r]=0.f; oacc1[r]=0.f; }
  float mrow = -1e30f, lrow = 0.f;

  // staging source (lane-dep, tile-invariant): sigma = swap bits2<->3 of row
  const int sig = (lane & 0x33) | ((lane & 8) >> 1) | ((lane & 4) << 1);
  const bf16* ksrcL = Kg  + ((size_t)bh*SEQ + sig)*DKH;
  const bf16* vsrcL = Vtg + ((size_t)bh*DKH + lane)*SEQ;
  const int jb0 = half*1024;
  const int lbase = hi*512 + q5*8;

  auto STAGE = [&](int t, int nb){
    const int j0 = jb0 + t*64;
    #pragma unroll
    for (int i=0;i<2;i++){
      const int dblk = i*4 + wl;
      gload_lds16(ksrcL + (size_t)j0*DKH + dblk*8, &kv_lds[half][nb][0][dblk*512]);
      gload_lds16(vsrcL + j0 + dblk*8,             &kv_lds[half][nb][1][dblk*512]);
    }
    if (wl < 2){
      const int chunk = wl*64 + lane;
      const int tcls = chunk>>4, c16 = chunk&15;
      const int jsw = (c16<<2) ^ (tcls<<3);
      gload_lds16(biasg + ((size_t)(bh*RTYPES + tcls))*SEQ + j0 + jsw,
                  &bias_lds[half][nb][wl*256]);
    }
  };

  auto COMPUTE = [&](int nb){
    const bf16*  kb_ = &kv_lds[half][nb][0][0];
    const bf16*  vb_ = &kv_lds[half][nb][1][0];
    const float* bb_ = &bias_lds[half][nb][0];

    // C-init from bias; s[nt] reg r: j = nt*32+(r&3)+4*((r>>2)&1)+8*hi+16*(r>>3)
    f32x16v s0, s1;
    #pragma unroll
    for (int g4=0; g4<4; g4++){
      f32x4v b0 = *(const f32x4v*)&bb_[boff[0][g4]];
      f32x4v b1 = *(const f32x4v*)&bb_[boff[1][g4]];
      #pragma unroll
      for (int rr=0; rr<4; rr++){ s0[g4*4+rr] = b0[rr]; s1[g4*4+rr] = b1[rr]; }
    }

    // S^T = K Q^T (+bias)
    #pragma unroll
    for (int kc=0;kc<4;kc++){
      bf16x8v kf0 = *(const bf16x8v*)(kb_ + lbase + kc*1024);
      bf16x8v kf1 = *(const bf16x8v*)(kb_ + lbase + kc*1024 + 256);
      s0 = mfma32(kf0, qf[kc], s0);
      s1 = mfma32(kf1, qf[kc], s1);
    }

    // row max (max3 tree) + 1 cross-half shuffle
    float a0 = fmaxf(fmaxf(s0[0],s0[1]),s0[2]);
    float a1 = fmaxf(fmaxf(s0[3],s0[4]),s0[5]);
    float a2 = fmaxf(fmaxf(s0[6],s0[7]),s0[8]);
    float a3 = fmaxf(fmaxf(s0[9],s0[10]),s0[11]);
    float a4 = fmaxf(fmaxf(s0[12],s0[13]),s0[14]);
    float a5 = fmaxf(fmaxf(s0[15],s1[0]),s1[1]);
    float a6 = fmaxf(fmaxf(s1[2],s1[3]),s1[4]);
    float a7 = fmaxf(fmaxf(s1[5],s1[6]),s1[7]);
    float a8 = fmaxf(fmaxf(s1[8],s1[9]),s1[10]);
    float a9 = fmaxf(fmaxf(s1[11],s1[12]),s1[13]);
    float aA = fmaxf(s1[14],s1[15]);
    float b0 = fmaxf(fmaxf(a0,a1),a2);
    float b1 = fmaxf(fmaxf(a3,a4),a5);
    float b2 = fmaxf(fmaxf(a6,a7),a8);
    float b3 = fmaxf(a9,aA);
    float mx = fmaxf(fmaxf(b0,b1), fmaxf(b2,b3));
    mx = fmaxf(mx, __shfl_xor(mx, 32));

    // defer-max (THR=8, exp2 units)
    if (!__all(mx - mrow <= 8.0f)){
      float mnew = fmaxf(mrow, mx);
      float scl = exp2f(mrow - mnew);
      #pragma unroll
      for (int r=0;r<16;r++){ oacc0[r] *= scl; oacc1[r] *= scl; }
      lrow *= scl;
      mrow = mnew;
    }

    #pragma unroll
    for (int r=0;r<16;r++){ s0[r] = exp2f(s0[r] - mrow); s1[r] = exp2f(s1[r] - mrow); }

    // row-sum (VALU tree) + cross-half shuffle
    float t0 = 0.f, t1 = 0.f;
    #pragma unroll
    for (int r=0;r<16;r++){ t0 += s0[r]; t1 += s1[r]; }
    float sum = t0 + t1;
    sum += __shfl_xor(sum, 32);
    lrow += sum;

    // P fragments: contiguous register renames
    bf16x8v pa0, pa1, pa2, pa3;
    #pragma unroll
    for (int e=0;e<8;e++){
      pa0[e] = (bf16)s0[e];   pa1[e] = (bf16)s0[e+8];
      pa2[e] = (bf16)s1[e];   pa3[e] = (bf16)s1[e+8];
    }

    // O^T += V^T P
    #pragma unroll
    for (int m=0;m<4;m++){
      bf16x8v vf0 = *(const bf16x8v*)(vb_ + lbase + m*1024);
      bf16x8v vf1 = *(const bf16x8v*)(vb_ + lbase + m*1024 + 256);
      bf16x8v pm = (m==0)?pa0:(m==1)?pa1:(m==2)?pa2:pa3;
      oacc0 = mfma32(vf0, pm, oacc0);
      oacc1 = mfma32(vf1, pm, oacc1);
    }
  };

  // ---- 2-buffer m97-style loop ----
  STAGE(0, 0);
  __syncthreads();
  int cur = 0;
  #pragma unroll 1
  for (int t=0; t<NTl; ++t){
    if (t+1 < NTl) STAGE(t+1, cur^1);
    COMPUTE(cur);
    __syncthreads();
    cur ^= 1;
  }

  // ---- in-block LSE merge (overlay kv_lds) ----
  float* mrg = (float*)&kv_lds[0][0][0][0];    // [pair p][q5][68]: 64 O + m + l
  if (half == 1){
    float* row = mrg + (wl*32 + q5)*68;
    #pragma unroll
    for (int rq=0;rq<4;rq++){
      f32x4v t0v, t1v;
      #pragma unroll
      for (int k=0;k<4;k++){ t0v[k] = oacc0[rq*4+k]; t1v[k] = oacc1[rq*4+k]; }
      *(f32x4v*)(row + 0  + rq*8 + hi*4) = t0v;
      *(f32x4v*)(row + 32 + rq*8 + hi*4) = t1v;
    }
    if (hi == 0){ row[64] = mrow; row[65] = lrow; }
  }
  __syncthreads();
  if (half == 0){
    const float* row = mrg + (wl*32 + q5)*68;
    const float m1 = row[64], l1 = row[65];
    const float M  = fmaxf(mrow, m1);
    const float s0c = exp2f(mrow - M), s1c = exp2f(m1 - M);
    const float inv = 1.0f / (lrow*s0c + l1*s1c);
    bf16* orow = &Og[(size_t)(b*SEQ + qrow)*D_MODEL + h*DKH];
    #pragma unroll
    for (int rq=0;rq<4;rq++){
      f32x4v o1a = *(const f32x4v*)(row + 0  + rq*8 + hi*4);
      f32x4v o1b = *(const f32x4v*)(row + 32 + rq*8 + hi*4);
      bf16x4v ov0, ov1;
      #pragma unroll
      for (int k=0;k<4;k++){
        ov0[k] = (bf16)((oacc0[rq*4+k]*s0c + o1a[k]*s1c) * inv);
        ov1[k] = (bf16)((oacc1[rq*4+k]*s0c + o1b[k]*s1c) * inv);
      }
      const int d = 8*rq + 4*hi;
      *(bf16x4v*)(orow + d)      = ov0;
      *(bf16x4v*)(orow + 32 + d) = ov1;
    }
  }
}

// ---------------- launch ----------------
extern "C" void kernel_launch(void* const* d_in, const int* in_sizes, int n_in,
                              void* d_out, int out_size, void* d_ws, size_t ws_size,
                              hipStream_t stream)
{
  (void)in_sizes; (void)n_in; (void)out_size; (void)ws_size;
  const float* x     = (const float*)d_in[0];
  const float* Wq    = (const float*)d_in[1];
  const float* bq    = (const float*)d_in[2];
  const float* Wk    = (const float*)d_in[3];
  const float* bk    = (const float*)d_in[4];
  const float* Wv    = (const float*)d_in[5];
  const float* bv    = (const float*)d_in[6];
  const float* Wo    = (const float*)d_in[7];
  const float* bo    = (const float*)d_in[8];
  const float* rbias = (const float*)d_in[9];
  const int*   rmask = (const int*)d_in[10];
  const int*   amask = (const int*)d_in[11];
  float* out = (float*)d_out;

  char* ws = (char*)d_ws;
  bf16*  xb    = (bf16*)(ws);                 //  8 MB
  bf16*  wqb   = (bf16*)(ws + (8u<<20));      //  2 MB each
  bf16*  wkb   = (bf16*)(ws + (10u<<20));
  bf16*  wvb   = (bf16*)(ws + (12u<<20));
  bf16*  wob   = (bf16*)(ws + (14u<<20));
  bf16*  qb    = (bf16*)(ws + (16u<<20));     //  8 MB Q (pre-scaled, exp2 domain)
  bf16*  kb    = (bf16*)(ws + (24u<<20));     //  8 MB K
  bf16*  vtb   = (bf16*)(ws + (32u<<20));     //  8 MB V^T
  bf16*  aob   = (bf16*)(ws + (40u<<20));     //  8 MB attn out [s][e]
  float* biasg = (float*)(ws + (48u<<20));    //  2 MB bias [b][h][8][S]

  convert_kernel<<<9216, 256, 0, stream>>>(x,Wq,Wk,Wv,Wo, xb,wqb,wkb,wvb,wob,
                                           rbias, rmask, amask, biasg);

  GemmOuts qkv;
  qkv.W[0]=wqb; qkv.W[1]=wkb; qkv.W[2]=wvb;
  qkv.bia[0]=bq; qkv.bia[1]=bk; qkv.bia[2]=bv;
  qkv.out[0]=qb; qkv.out[1]=kb; qkv.out[2]=vtb;
  gemm_bt_kernel<1><<<dim3(D_MODEL/128, MROWS/128, 3), 256, 0, stream>>>(xb, qkv, 0.125f*LOG2E);

  attn7_kernel<<<dim3(SEQ/128, NHEADS, NBATCH), 512, 0, stream>>>(qb, kb, vtb, biasg, rmask, aob);

  GemmOuts og;
  og.W[0]=wob; og.W[1]=wob; og.W[2]=wob;
  og.bia[0]=bo; og.bia[1]=bo; og.bia[2]=bo;
  og.out[0]=out; og.out[1]=out; og.out[2]=out;
  gemm_bt_kernel<0><<<dim3(D_MODEL/128, MROWS/128), 256, 0, stream>>>(aob, og, 1.0f);
}